// Round 3
// 148.833 us; speedup vs baseline: 1.0720x; 1.0720x over previous
//
#include <hip/hip_runtime.h>
#include <hip/hip_bf16.h>

// Problem constants (NoiseEfficientNet): B=32, Cin=96, Cout=144, H=W=56, 3x3 pad1
#define B_    32
#define CIN   96
#define COUT  144
#define H_    56
#define W_    56
#define HW    3136      // 56*56
#define NPIX  100352    // 32*3136
#define KTOT  864       // 9 taps * 96 ci
#define MT    256       // workgroup pixel tile (4 waves x 64 pixels each)
#define TAPSZ (COUT*CIN) // 13824 shorts per tap in Wt

typedef short  short8  __attribute__((ext_vector_type(8)));
typedef float  floatx4 __attribute__((ext_vector_type(4)));

// zero pool for halo-fragment redirection (zero-initialized device memory).
// Max offset added to the redirected base: ks*32 + q*8 + 8 = 128 shorts = 256 B.
__device__ __attribute__((aligned(64))) float g_zero[64];   // 256 B of zeros

__device__ __forceinline__ unsigned short f2bf(float f) {
    union { float f; unsigned int u; } v; v.f = f;
    unsigned int u = v.u;
    return (unsigned short)((u + 0x7FFFu + ((u >> 16) & 1u)) >> 16);  // RNE
}

// async global->LDS, 16B per lane; LDS dest is wave-uniform base + lane*16
__device__ __forceinline__ void glds16(const void* g, void* l) {
    __builtin_amdgcn_global_load_lds(
        (const __attribute__((address_space(1))) unsigned int*)g,
        (__attribute__((address_space(3))) unsigned int*)l, 16, 0, 0);
}

// ---------------------------------------------------------------------------
// Fused prep kernel.
//   transpose: x [B][96][56][56] f32 -> xT [B][56][56][96] bf16
//   weights:   Wm [144][96][3][3] f32 -> Wt [tap][g][co][8] bf16
//              (g = ci-granule 0..11; slab per tap is contiguous in the exact
//               order conv_gemm's glds staging walks it -> coalesced sources,
//               and the LDS image/read addressing stay identical to before)
//   E table:   E [B][144][3][3] f32 (boundary-class constants for extra path)
// ---------------------------------------------------------------------------
#define TB 1568
#define WB 486
__global__ __launch_bounds__(256) void prep_all(const float* __restrict__ x,
                                                unsigned short* __restrict__ xT,
                                                const float* __restrict__ Wm,
                                                unsigned short* __restrict__ Wt,
                                                const float* __restrict__ extra,
                                                const float* __restrict__ Wx,
                                                const float* __restrict__ bm,
                                                const float* __restrict__ bx,
                                                float* __restrict__ E) {
    __shared__ __align__(16) unsigned short tile[64][CIN + 8];
    int blk = blockIdx.x;
    int t = threadIdx.x;
    if (blk < TB) {
        int b   = blk / 49;
        int hw0 = (blk % 49) * 64;
        const float* xb = x + (size_t)b * CIN * HW;
        for (int i = t; i < CIN * 16; i += 256) {
            int ci = i >> 4, seg = i & 15;
            float4 v = *(const float4*)(xb + (size_t)ci * HW + hw0 + seg * 4);
            int hwl = seg * 4;
            tile[hwl + 0][ci] = f2bf(v.x);
            tile[hwl + 1][ci] = f2bf(v.y);
            tile[hwl + 2][ci] = f2bf(v.z);
            tile[hwl + 3][ci] = f2bf(v.w);
        }
        __syncthreads();
        int row = t >> 2, part = t & 3;
        const uint4* s = (const uint4*)&tile[row][part * 24];
        uint4* d = (uint4*)(xT + ((size_t)b * HW + hw0 + row) * CIN + part * 24);
        d[0] = s[0]; d[1] = s[1]; d[2] = s[2];
    } else if (blk < TB + WB) {
        int i = (blk - TB) * 256 + t;      // [0, 124416)
        // Wt layout: [tap][g][co][e]  (13824 = 12*144*8 per tap, 1152 = 144*8)
        int tap = i / 13824;
        int r1  = i - tap * 13824;
        int g   = r1 / 1152;
        int r2  = r1 - g * 1152;
        int co  = r2 >> 3;
        int e   = r2 & 7;
        int ci  = g * 8 + e;
        Wt[i] = f2bf(Wm[((size_t)co * CIN + ci) * 9 + tap]);
    } else {
        int i = (blk - TB - WB) * 256 + t; // [0, 4608)
        int b = i / COUT, co = i - b * COUT;
        float base = bm[co] + bx[co];
        float m[3][3] = {{0,0,0},{0,0,0},{0,0,0}};
        for (int f = 0; f < 3; ++f) {
            float e = extra[(size_t)b * (COUT * 3) + co * 3 + f];
            const float* w = Wx + ((size_t)co * 3 + f) * 9;
            for (int rc = 0; rc < 3; ++rc) {
                int kh0 = (rc == 0) ? 1 : 0;
                int kh1 = (rc == 2) ? 1 : 2;
                for (int cc = 0; cc < 3; ++cc) {
                    int kw0 = (cc == 0) ? 1 : 0;
                    int kw1 = (cc == 2) ? 1 : 2;
                    float s = 0.f;
                    for (int kh = kh0; kh <= kh1; ++kh)
                        for (int kw = kw0; kw <= kw1; ++kw)
                            s += w[kh * 3 + kw];
                    m[rc][cc] += e * s;
                }
            }
        }
        float* dst = E + (size_t)i * 9;
        for (int rc = 0; rc < 3; ++rc)
            for (int cc = 0; cc < 3; ++cc)
                dst[rc * 3 + cc] = base + m[rc][cc];
    }
}

// ---------------------------------------------------------------------------
// Main implicit GEMM v4 (v3 algorithm, rolled tap loop for gentle codegen).
// Block: 256 thr = 4 waves; tile 256 px x 144 co; wave = 64 px x 144 co.
//  * Wt [tap][g][co][8] -> glds staging sources are lane-linear (1 KiB
//    contiguous per instruction); LDS image / ds_read addressing unchanged.
//  * A fragments single-buffered with rotating prefetch (phase ks's MFMAs
//    consume a[*][ks], then next tap's a[*][ks] loads into the same regs).
//  * tap loop is NOT unrolled (9 iterations, ks/n/ms inner loops unrolled):
//    all register-array indices stay compile-time-constant, code ~9x smaller,
//    register allocator pressure low -> __launch_bounds__(256,2) reachable:
//    2 waves/SIMD, 2 blocks/CU, whole 392-block grid co-resident in one round.
// Epilogue: direct stores from acc D-layout (col=lane&15 -> co,
// row=(lane>>4)*4+reg -> px), 64B runs per co per instr, L2-merged.
// ---------------------------------------------------------------------------
__global__ __launch_bounds__(256, 2) void conv_gemm(const unsigned short* __restrict__ xT,
                                                    const unsigned short* __restrict__ Wt,
                                                    const float* __restrict__ E,
                                                    float* __restrict__ out) {
    __shared__ __align__(16) unsigned short Bs[2 * TAPSZ];   // 2 x 27648 B

    int tid = threadIdx.x;
    int wv = tid >> 6, lane = tid & 63;
    int r16 = lane & 15, q = lane >> 4;
    int pixBase = blockIdx.x * MT;

    floatx4 acc[4][9];
    #pragma unroll
    for (int m = 0; m < 4; ++m)
        #pragma unroll
        for (int n = 0; n < 9; ++n)
            acc[m][n] = (floatx4){0.f, 0.f, 0.f, 0.f};

    // ---- A addressing (per ms-subtile, tap-invariant) ----
    int aIdx[4], hA[4], wA[4];
    #pragma unroll
    for (int ms = 0; ms < 4; ++ms) {
        int p = pixBase + wv * 64 + ms * 16 + r16;   // A-frag m = lane&15
        aIdx[ms] = p * CIN;
        int hw = p % HW;
        hA[ms] = hw / W_;
        wA[ms] = hw - hA[ms] * W_;
    }
    const unsigned short* gz = (const unsigned short*)g_zero;

    const bool bTail = (tid < 192);   // waves 0-2 stage slots [1536,1728)

    // B-frag read base (shorts): addr(n,ks) = Bp + ks*4608 + n*128
    const unsigned short* BpBase = Bs + (q * COUT + r16) * 8;

    // ---- single-buffered A fragments (rotating prefetch) ----
    short8 a[4][3];

    // ---- prologue: stage tap 0 (linear sources) + load tap 0 A ----
    {
        const unsigned short* wsrc = Wt;
        #pragma unroll
        for (int j = 0; j < 6; ++j)
            glds16(wsrc + tid * 8 + j * 2048, (void*)(Bs + tid * 8 + j * 2048));
        if (bTail)
            glds16(wsrc + tid * 8 + 6 * 2048, (void*)(Bs + tid * 8 + 6 * 2048));
        const int dh = -1, dw = -1, off = (dh * W_ + dw) * CIN;
        #pragma unroll
        for (int ms = 0; ms < 4; ++ms) {
            bool valid = ((unsigned)(hA[ms] + dh) < H_) && ((unsigned)(wA[ms] + dw) < W_);
            const unsigned short* base = valid ? (xT + aIdx[ms] + off) : gz;
            #pragma unroll
            for (int ks = 0; ks < 3; ++ks)
                a[ms][ks] = *(const short8*)(base + ks * 32 + q * 8);
        }
    }
    __syncthreads();   // tap 0 B in LDS, A in regs

    #pragma unroll 1
    for (int tap = 0; tap < 9; ++tap) {
        const int cur = tap & 1, nxt = cur ^ 1;
        const bool pf = (tap < 8);

        // ---- issue next tap's B-glds + compute next-tap A bases ----
        const unsigned short* aBase[4];
        if (pf) {
            const int tap2 = tap + 1;
            const int r3   = tap2 / 3;
            const int dh2  = r3 - 1, dw2 = tap2 - r3 * 3 - 1;
            const unsigned short* wsrc = Wt + tap2 * TAPSZ;
            unsigned short* bd = Bs + nxt * TAPSZ;
            #pragma unroll
            for (int j = 0; j < 6; ++j)
                glds16(wsrc + tid * 8 + j * 2048, (void*)(bd + tid * 8 + j * 2048));
            if (bTail)
                glds16(wsrc + tid * 8 + 6 * 2048, (void*)(bd + tid * 8 + 6 * 2048));
            const int off2 = (dh2 * W_ + dw2) * CIN;
            #pragma unroll
            for (int ms = 0; ms < 4; ++ms) {
                bool valid = ((unsigned)(hA[ms] + dh2) < H_) && ((unsigned)(wA[ms] + dw2) < W_);
                aBase[ms] = valid ? (xT + aIdx[ms] + off2) : gz;
            }
        } else {
            #pragma unroll
            for (int ms = 0; ms < 4; ++ms)
                aBase[ms] = gz;   // dead reload target on last tap
        }

        // ---- compute tap: 3 k-subtiles x (9 n x 4 ms) MFMAs; after phase ks
        //      consumes a[*][ks], reload it with next tap's fragment ----
        const unsigned short* Bp = BpBase + cur * TAPSZ;
        #pragma unroll
        for (int ks = 0; ks < 3; ++ks) {
            #pragma unroll
            for (int n3 = 0; n3 < 3; ++n3) {
                short8 b0 = *(const short8*)(Bp + ks * 4608 + (n3 * 3 + 0) * 128);
                short8 b1 = *(const short8*)(Bp + ks * 4608 + (n3 * 3 + 1) * 128);
                short8 b2 = *(const short8*)(Bp + ks * 4608 + (n3 * 3 + 2) * 128);
                #pragma unroll
                for (int ms = 0; ms < 4; ++ms)
                    acc[ms][n3 * 3 + 0] = __builtin_amdgcn_mfma_f32_16x16x32_bf16(
                        a[ms][ks], b0, acc[ms][n3 * 3 + 0], 0, 0, 0);
                #pragma unroll
                for (int ms = 0; ms < 4; ++ms)
                    acc[ms][n3 * 3 + 1] = __builtin_amdgcn_mfma_f32_16x16x32_bf16(
                        a[ms][ks], b1, acc[ms][n3 * 3 + 1], 0, 0, 0);
                #pragma unroll
                for (int ms = 0; ms < 4; ++ms)
                    acc[ms][n3 * 3 + 2] = __builtin_amdgcn_mfma_f32_16x16x32_bf16(
                        a[ms][ks], b2, acc[ms][n3 * 3 + 2], 0, 0, 0);
            }
            // rotate in next tap's A fragment for this k-subtile
            #pragma unroll
            for (int ms = 0; ms < 4; ++ms)
                a[ms][ks] = *(const short8*)(aBase[ms] + ks * 32 + q * 8);
        }

        // drain next tap's glds+A-loads (had the whole compute phase to land)
        // + release cur buffer for tap+2's staging.
        __syncthreads();
    }

    // ---- epilogue: direct stores, out = acc + E[b][co][rc(h)][cc(w)] ----
    #pragma unroll
    for (int ms = 0; ms < 4; ++ms) {
        int p0 = pixBase + wv * 64 + ms * 16 + q * 4;  // D-layout row = q*4+reg
        int b  = p0 / HW;
        int hw0 = p0 - b * HW;                          // 4-aligned, no b straddle
        int h = hw0 / W_;
        int w0 = hw0 - h * W_;                          // 4-aligned, no row straddle
        int rc = (h == 0) ? 0 : ((h == H_ - 1) ? 2 : 1);
        int cc0 = (w0 == 0) ? 0 : ((w0 == W_ - 1) ? 2 : 1);
        int cc1 = (w0 + 1 == W_ - 1) ? 2 : 1;
        int cc2 = (w0 + 2 == W_ - 1) ? 2 : 1;
        int cc3 = (w0 + 3 == W_ - 1) ? 2 : 1;
        const float* Ebase = E + (size_t)b * COUT * 9 + rc * 3;
        float* outB = out + (size_t)b * COUT * HW + hw0;
        #pragma unroll
        for (int n = 0; n < 9; ++n) {
            int co = n * 16 + r16;                      // D-layout col = lane&15
            const float* Eb = Ebase + co * 9;
            float4 v;
            v.x = acc[ms][n][0] + Eb[cc0];
            v.y = acc[ms][n][1] + Eb[cc1];
            v.z = acc[ms][n][2] + Eb[cc2];
            v.w = acc[ms][n][3] + Eb[cc3];
            *(float4*)(outB + (size_t)co * HW) = v;
        }
    }
}

// ---------------------------------------------------------------------------
extern "C" void kernel_launch(void* const* d_in, const int* in_sizes, int n_in,
                              void* d_out, int out_size, void* d_ws, size_t ws_size,
                              hipStream_t stream) {
    const float* x     = (const float*)d_in[0];
    const float* extra = (const float*)d_in[1];
    const float* Wm    = (const float*)d_in[2];
    const float* bm    = (const float*)d_in[3];
    const float* Wx    = (const float*)d_in[4];
    const float* bx    = (const float*)d_in[5];
    float* out = (float*)d_out;

    const size_t XT_BYTES = (size_t)NPIX * CIN * 2;    // 19,267,584
    const size_t WT_BYTES = (size_t)COUT * KTOT * 2;   //    248,832
    const size_t E_BYTES  = (size_t)B_ * COUT * 9 * 4; //    165,888
    if (ws_size < XT_BYTES + WT_BYTES + E_BYTES) return;

    unsigned short* xT = (unsigned short*)d_ws;
    unsigned short* Wt = (unsigned short*)((char*)d_ws + XT_BYTES);
    float*          E  = (float*)((char*)d_ws + XT_BYTES + WT_BYTES);

    prep_all<<<TB + WB + 18, 256, 0, stream>>>(x, xT, Wm, Wt, extra, Wx, bm, bx, E);
    conv_gemm<<<NPIX / MT, 256, 0, stream>>>(xT, Wt, E, out);
}